// Round 7
// baseline (122.363 us; speedup 1.0000x reference)
//
#include <hip/hip_runtime.h>

// Corr1d_x_group: out[n, g*27+ch, h, w] =
//   0.25 * sum_{c<4} l[n, g*4+c, h, w] * r[n, g*4+c, h, w+ch-23]   (0 if shifted w out of [0,W))
// fp32, N=8, Cin=16, H=256, W=512. Memory-bound: 432 MiB out + 128 MiB in.
// Round 7: round-4 structure (best: 106.7us) + NT stores restored + bijective
// XCD-chunked blockIdx swizzle: each XCD owns 4 complete (n,g) groups, so its
// 27 output-plane write streams advance sequentially in h (DRAM page locality).

#define TOP 27
#define GRP 4
#define CPG 4
#define HH 256
#define WW 512
#define NN 8
#define CIN 16
#define PADL 24                 // rsm[c][PADL + w] = r[w]; [0..23] and [536..547] zero halo
#define RROW (WW + 36)          // 548 floats
#define NWG (NN * GRP * HH)     // 8192, divisible by 8 XCDs -> simple swizzle bijective

typedef float f32x2 __attribute__((ext_vector_type(2)));

__global__ __launch_bounds__(256) void corr1d_kernel(
    const float* __restrict__ l, const float* __restrict__ r, float* __restrict__ out)
{
    const int t = threadIdx.x;           // 0..255, owns w = 2t, 2t+1
    const int w0 = 2 * t;

    // XCD-chunked swizzle: hardware assigns block i to XCD i%8; remap so XCD k
    // processes work ids [k*1024, (k+1)*1024) = 4 complete (n,g) groups, h-ordered.
    const int orig = blockIdx.x;
    int b = (orig & 7) * (NWG / 8) + (orig >> 3);

    const int h = b & (HH - 1);
    b >>= 8;
    const int g = b & (GRP - 1);
    const int n = b >> 2;

    __shared__ __align__(16) float rsm[CPG][RROW];

    const size_t HWs = (size_t)HH * WW;
    const float* lbase = l + (((size_t)n * CIN + (size_t)g * CPG) * HH + h) * WW;
    const float* rbase = r + (((size_t)n * CIN + (size_t)g * CPG) * HH + h) * WW;

    f32x2 lv[CPG];
#pragma unroll
    for (int c = 0; c < CPG; ++c) {
        lv[c] = __builtin_nontemporal_load((const f32x2*)(lbase + c * HWs + w0));
        f32x2 rv2 = __builtin_nontemporal_load((const f32x2*)(rbase + c * HWs + w0));
        *(f32x2*)&rsm[c][PADL + w0] = rv2;
    }
    // zero halos: [0..23] and [536..547]
    if (t < 24) {
#pragma unroll
        for (int c = 0; c < CPG; ++c) rsm[c][t] = 0.0f;
    } else if (t >= 256 - 12) {
        const int i = t - 244;           // 0..11 -> 536..547
#pragma unroll
        for (int c = 0; c < CPG; ++c) rsm[c][536 + i] = 0.0f;
    }
    __syncthreads();

    float* obase = out + (((size_t)n * (GRP * TOP) + (size_t)g * TOP) * HH + h) * WW + w0;

    // 3 chunks of 9 displacement channels. out index = PADL + w + ch - 23 = w0 + 1 + j + ch.
    const int c0s[3]  = {0, 9, 18};
    const int offs[3] = {0, 10, 18};     // even window bases
    const int ibs[3]  = {1, 0, 1};       // rv index of (j=0, ch'=0)

#pragma unroll
    for (int kk = 0; kk < 3; ++kk) {
        const int c0 = c0s[kk], off = offs[kk], ib = ibs[kk];
        float acc0[9], acc1[9];
#pragma unroll
        for (int ch = 0; ch < 9; ++ch) { acc0[ch] = 0.0f; acc1[ch] = 0.0f; }

#pragma unroll
        for (int c = 0; c < CPG; ++c) {
            float rv[12];
#pragma unroll
            for (int k = 0; k < 6; ++k) {
                f32x2 v = *(const f32x2*)&rsm[c][w0 + off + 2 * k];
                rv[2 * k]     = v.x;
                rv[2 * k + 1] = v.y;
            }
            const float a0 = lv[c].x, a1 = lv[c].y;
#pragma unroll
            for (int ch = 0; ch < 9; ++ch) {
                acc0[ch] += a0 * rv[ib + ch];
                acc1[ch] += a1 * rv[ib + ch + 1];
            }
        }
#pragma unroll
        for (int ch = 0; ch < 9; ++ch) {
            f32x2 o;
            o.x = acc0[ch] * 0.25f;
            o.y = acc1[ch] * 0.25f;
            __builtin_nontemporal_store(o, (f32x2*)(obase + (size_t)(c0 + ch) * HWs));
        }
    }
}

extern "C" void kernel_launch(void* const* d_in, const int* in_sizes, int n_in,
                              void* d_out, int out_size, void* d_ws, size_t ws_size,
                              hipStream_t stream) {
    const float* l = (const float*)d_in[0];
    const float* r = (const float*)d_in[1];
    float* out = (float*)d_out;
    dim3 grid(NWG);   // 8192 blocks: one per (n, g, h) row
    corr1d_kernel<<<grid, 256, 0, stream>>>(l, r, out);
}

// Round 8
// 105.054 us; speedup vs baseline: 1.1648x; 1.1648x over previous
//
#include <hip/hip_runtime.h>

// Corr1d_x_group: out[n, g*27+ch, h, w] =
//   0.25 * sum_{c<4} l[n, g*4+c, h, w] * r[n, g*4+c, h, w+ch-23]   (0 if shifted w out of [0,W))
// fp32, N=8, Cin=16, H=256, W=512. Memory-bound: 432 MiB out + 128 MiB in.
// FINAL (= round-4 best, 106.7us = 5.5 TB/s effective):
//   - one 256-thread block per (n,g,h) row; 2 w/thread (f32x2)
//   - r row staged in LDS with zero halo (exact pad semantics)
//   - 3 chunks of 9 displacement channels -> ~64 VGPR, 8 waves/SIMD
//   - NT loads AND stores (NT stores measured +4% vs normal; zero reuse)
//   - no XCD swizzle (measured -15%: default round-robin interleave is optimal
//     for pure streaming, no inter-block reuse to exploit)
// Knobs tested and rejected: 16B/lane stores (neutral at low occ, -8% chunked),
// normal stores (-4%), XCD-chunked swizzle (-15%).

#define TOP 27
#define GRP 4
#define CPG 4
#define HH 256
#define WW 512
#define NN 8
#define CIN 16
#define PADL 24                 // rsm[c][PADL + w] = r[w]; [0..23] and [536..547] zero halo
#define RROW (WW + 36)          // 548 floats

typedef float f32x2 __attribute__((ext_vector_type(2)));

__global__ __launch_bounds__(256) void corr1d_kernel(
    const float* __restrict__ l, const float* __restrict__ r, float* __restrict__ out)
{
    const int t = threadIdx.x;           // 0..255, owns w = 2t, 2t+1
    const int w0 = 2 * t;
    int b = blockIdx.x;                  // n*GRP*HH + g*HH + h
    const int h = b & (HH - 1);
    b >>= 8;
    const int g = b & (GRP - 1);
    const int n = b >> 2;

    __shared__ __align__(16) float rsm[CPG][RROW];

    const size_t HWs = (size_t)HH * WW;
    const float* lbase = l + (((size_t)n * CIN + (size_t)g * CPG) * HH + h) * WW;
    const float* rbase = r + (((size_t)n * CIN + (size_t)g * CPG) * HH + h) * WW;

    f32x2 lv[CPG];
#pragma unroll
    for (int c = 0; c < CPG; ++c) {
        lv[c] = __builtin_nontemporal_load((const f32x2*)(lbase + c * HWs + w0));
        f32x2 rv2 = __builtin_nontemporal_load((const f32x2*)(rbase + c * HWs + w0));
        *(f32x2*)&rsm[c][PADL + w0] = rv2;
    }
    // zero halos: [0..23] and [536..547]
    if (t < 24) {
#pragma unroll
        for (int c = 0; c < CPG; ++c) rsm[c][t] = 0.0f;
    } else if (t >= 256 - 12) {
        const int i = t - 244;           // 0..11 -> 536..547
#pragma unroll
        for (int c = 0; c < CPG; ++c) rsm[c][536 + i] = 0.0f;
    }
    __syncthreads();

    float* obase = out + (((size_t)n * (GRP * TOP) + (size_t)g * TOP) * HH + h) * WW + w0;

    // 3 chunks of 9 displacement channels. out index = PADL + w + ch - 23 = w0 + 1 + j + ch.
    const int c0s[3]  = {0, 9, 18};
    const int offs[3] = {0, 10, 18};     // even window bases
    const int ibs[3]  = {1, 0, 1};       // rv index of (j=0, ch'=0)

#pragma unroll
    for (int kk = 0; kk < 3; ++kk) {
        const int c0 = c0s[kk], off = offs[kk], ib = ibs[kk];
        float acc0[9], acc1[9];
#pragma unroll
        for (int ch = 0; ch < 9; ++ch) { acc0[ch] = 0.0f; acc1[ch] = 0.0f; }

#pragma unroll
        for (int c = 0; c < CPG; ++c) {
            float rv[12];
#pragma unroll
            for (int k = 0; k < 6; ++k) {
                f32x2 v = *(const f32x2*)&rsm[c][w0 + off + 2 * k];
                rv[2 * k]     = v.x;
                rv[2 * k + 1] = v.y;
            }
            const float a0 = lv[c].x, a1 = lv[c].y;
#pragma unroll
            for (int ch = 0; ch < 9; ++ch) {
                acc0[ch] += a0 * rv[ib + ch];
                acc1[ch] += a1 * rv[ib + ch + 1];
            }
        }
#pragma unroll
        for (int ch = 0; ch < 9; ++ch) {
            f32x2 o;
            o.x = acc0[ch] * 0.25f;
            o.y = acc1[ch] * 0.25f;
            __builtin_nontemporal_store(o, (f32x2*)(obase + (size_t)(c0 + ch) * HWs));
        }
    }
}

extern "C" void kernel_launch(void* const* d_in, const int* in_sizes, int n_in,
                              void* d_out, int out_size, void* d_ws, size_t ws_size,
                              hipStream_t stream) {
    const float* l = (const float*)d_in[0];
    const float* r = (const float*)d_in[1];
    float* out = (float*)d_out;
    dim3 grid(NN * GRP * HH);   // 8192 blocks: one per (n, g, h) row
    corr1d_kernel<<<grid, 256, 0, stream>>>(l, r, out);
}